// Round 7
// baseline (441.508 us; speedup 1.0000x reference)
//
#include <hip/hip_runtime.h>

typedef _Float16 f16;
typedef _Float16 half8 __attribute__((ext_vector_type(8)));
typedef _Float16 half4 __attribute__((ext_vector_type(4)));
typedef float f32x4 __attribute__((ext_vector_type(4)));

#define B_ 2
#define S_ 2048
#define DM_ 2048
#define H_ 16
#define HD_ 128
#define EQ_ 6144              // (H + 2*HKV) * HD = 48*128
#define SCALE_Q 0.08838834764831845f   // 1/sqrt(128); natural-log softmax, __expf is fast
#define DEFER_THR 8.0f

// async global->LDS, 16B per lane; LDS dest is wave-uniform base + lane*16
__device__ __forceinline__ void gload16(const void* g, void* l) {
  __builtin_amdgcn_global_load_lds(
      (const __attribute__((address_space(1))) unsigned int*)g,
      (__attribute__((address_space(3))) unsigned int*)l, 16, 0, 0);
}

// 16-lane reductions via DPP (VALU-speed, no DS pipe)
__device__ __forceinline__ float red16_max(float x) {
  float t;
  t = __builtin_bit_cast(float, __builtin_amdgcn_mov_dpp(__builtin_bit_cast(int, x), 0xB1, 0xF, 0xF, true));
  x = fmaxf(x, t);
  t = __builtin_bit_cast(float, __builtin_amdgcn_mov_dpp(__builtin_bit_cast(int, x), 0x4E, 0xF, 0xF, true));
  x = fmaxf(x, t);
  t = __builtin_bit_cast(float, __builtin_amdgcn_mov_dpp(__builtin_bit_cast(int, x), 0x141, 0xF, 0xF, true));
  x = fmaxf(x, t);
  t = __builtin_bit_cast(float, __builtin_amdgcn_mov_dpp(__builtin_bit_cast(int, x), 0x140, 0xF, 0xF, true));
  x = fmaxf(x, t);
  return x;
}
__device__ __forceinline__ float red16_sum(float x) {
  float t;
  t = __builtin_bit_cast(float, __builtin_amdgcn_mov_dpp(__builtin_bit_cast(int, x), 0xB1, 0xF, 0xF, true));
  x += t;
  t = __builtin_bit_cast(float, __builtin_amdgcn_mov_dpp(__builtin_bit_cast(int, x), 0x4E, 0xF, 0xF, true));
  x += t;
  t = __builtin_bit_cast(float, __builtin_amdgcn_mov_dpp(__builtin_bit_cast(int, x), 0x141, 0xF, 0xF, true));
  x += t;
  t = __builtin_bit_cast(float, __builtin_amdgcn_mov_dpp(__builtin_bit_cast(int, x), 0x140, 0xF, 0xF, true));
  x += t;
  return x;
}

// ---------------- cast fp32 -> fp16 (same layout) ----------------
__global__ void k_cast(const float* __restrict__ in, f16* __restrict__ out, int n4) {
  int i = blockIdx.x * blockDim.x + threadIdx.x;
  int stride = gridDim.x * blockDim.x;
  for (; i < n4; i += stride) {
    float4 v = ((const float4*)in)[i];
    half4 h = { (f16)v.x, (f16)v.y, (f16)v.z, (f16)v.w };
    ((half4*)out)[i] = h;
  }
}

// ------------- transpose+cast: in[K][N] fp32 -> out[N][K] fp16 -------------
__global__ void k_tcast(const float* __restrict__ in, f16* __restrict__ out, int K, int N) {
  __shared__ float tile[64][65];
  const int t = threadIdx.x;
  const int nb = blockIdx.x * 64, kb = blockIdx.y * 64;
  const int tr = t >> 4, tc4 = (t & 15) * 4;
  #pragma unroll
  for (int i = 0; i < 4; ++i) {
    int k = tr + i * 16;
    float4 v = *(const float4*)&in[(size_t)(kb + k) * N + nb + tc4];
    tile[k][tc4 + 0] = v.x; tile[k][tc4 + 1] = v.y;
    tile[k][tc4 + 2] = v.z; tile[k][tc4 + 3] = v.w;
  }
  __syncthreads();
  #pragma unroll
  for (int i = 0; i < 4; ++i) {
    int n = tr + i * 16;
    half4 h = { (f16)tile[tc4 + 0][n], (f16)tile[tc4 + 1][n],
                (f16)tile[tc4 + 2][n], (f16)tile[tc4 + 3][n] };
    *(half4*)&out[(size_t)(nb + n) * K + kb + tc4] = h;
  }
}

// ------- fp16 MFMA GEMM, 256x256 tile, 8 waves (2x4), per-wave 128x64 -------
// Same proven sync structure as the 128^2 kernel (2-buffer, prefetch-at-top,
// one barrier/tile) but 24 ds_read_b128 per 64 MFMA per wave (ratio 0.375):
// flips the per-CU balance from DS-pipe-bound (1536cy reads vs 1242cy MFMA)
// to MFMA-bound (2304 vs 2483). LDS 128KB -> 1 block/CU, 2 waves/SIMD.
__global__ __launch_bounds__(512, 2) void k_gemm256(
    const f16* __restrict__ A, const f16* __restrict__ Bt, f16* __restrict__ C,
    int N, int K)
{
  __shared__ __attribute__((aligned(16))) f16 As[2][256 * 64];
  __shared__ __attribute__((aligned(16))) f16 Bs[2][256 * 64];
  const int t = threadIdx.x;
  const int lane = t & 63, wave = t >> 6;
  const int lr = lane & 15, hi4 = lane >> 4;
  const int wm = wave >> 2, wn = wave & 3;     // 2 x 4 wave grid
  const int row0 = blockIdx.x * 256, col0 = blockIdx.y * 256;

  // staging: wave w covers rows [w*32, w*32+32) of each tile; lane l -> row
  // +i*8+(l>>3), chunk (l&7). Source chunk pre-swizzled (T2 both-sides rule):
  // LDS[row][c] = G[row][c ^ (row&7)]; (w*32+i*8) is 8-aligned so ^= srow.
  const int srow = lane >> 3, schunk = lane & 7;
  const f16* gA = &A[(size_t)(row0 + wave * 32 + srow) * K + ((schunk ^ srow) * 8)];
  const f16* gB = &Bt[(size_t)(col0 + wave * 32 + srow) * K + ((schunk ^ srow) * 8)];

  f32x4 acc[8][4];
  #pragma unroll
  for (int m = 0; m < 8; ++m)
    #pragma unroll
    for (int n = 0; n < 4; ++n)
      acc[m][n] = (f32x4){0.f, 0.f, 0.f, 0.f};

  const int nk = K >> 6;
  // prologue: tile 0 -> buf 0
  #pragma unroll
  for (int i = 0; i < 4; ++i) {
    gload16(gA + (size_t)(i * 8) * K, (char*)As[0] + wave * 4096 + i * 1024);
    gload16(gB + (size_t)(i * 8) * K, (char*)Bs[0] + wave * 4096 + i * 1024);
  }
  __syncthreads();

  for (int kt = 0; kt < nk; ++kt) {
    const int cur = kt & 1;
    if (kt + 1 < nk) {
      #pragma unroll
      for (int i = 0; i < 4; ++i) {
        gload16(gA + (size_t)(i * 8) * K + (kt + 1) * 64, (char*)As[cur ^ 1] + wave * 4096 + i * 1024);
        gload16(gB + (size_t)(i * 8) * K + (kt + 1) * 64, (char*)Bs[cur ^ 1] + wave * 4096 + i * 1024);
      }
    }
    const char* ab = (const char*)As[cur];
    const char* bb = (const char*)Bs[cur];
    #pragma unroll
    for (int ks = 0; ks < 2; ++ks) {
      half8 af[8], bf[4];
      #pragma unroll
      for (int m = 0; m < 8; ++m) {
        int ar = wm * 128 + m * 16 + lr;
        af[m] = *(const half8*)(ab + ar * 128 + (((ks * 4 + hi4) ^ (ar & 7)) << 4));
      }
      #pragma unroll
      for (int n = 0; n < 4; ++n) {
        int br = wn * 64 + n * 16 + lr;
        bf[n] = *(const half8*)(bb + br * 128 + (((ks * 4 + hi4) ^ (br & 7)) << 4));
      }
      __builtin_amdgcn_s_setprio(1);
      #pragma unroll
      for (int m = 0; m < 8; ++m)
        #pragma unroll
        for (int n = 0; n < 4; ++n)
          acc[m][n] = __builtin_amdgcn_mfma_f32_16x16x32_f16(af[m], bf[n], acc[m][n], 0, 0, 0);
      __builtin_amdgcn_s_setprio(0);
    }
    __syncthreads();   // drains vmcnt(0): prefetch landed; reads of cur done
  }
  #pragma unroll
  for (int m = 0; m < 8; ++m)
    #pragma unroll
    for (int n = 0; n < 4; ++n)
      #pragma unroll
      for (int j = 0; j < 4; ++j) {
        int row = row0 + wm * 128 + m * 16 + hi4 * 4 + j;
        int col = col0 + wn * 64 + n * 16 + lr;
        C[(size_t)row * N + col] = (f16)acc[m][n][j];
      }
}

// ---------------- fp16 MFMA GEMM: 128x128 tile (kept for gemm2) ----------------
__global__ __launch_bounds__(256, 2) void k_gemm(
    const f16* __restrict__ A, const f16* __restrict__ Bt,
    f16* __restrict__ C16, float* __restrict__ C32,
    int M, int N, int K, int writeF32)
{
  __shared__ __attribute__((aligned(16))) f16 As[2 * 128 * 64];  // 2 x 16KB
  __shared__ __attribute__((aligned(16))) f16 Bs[2 * 128 * 64];
  const int t = threadIdx.x;
  const int lane = t & 63, wave = t >> 6;
  const int lr = lane & 15, hi4 = lane >> 4;
  const int wr = wave >> 1, wc = wave & 1;
  const int row0 = blockIdx.x * 128, col0 = blockIdx.y * 128;

  const int srow = lane >> 3, schunk = lane & 7;
  const f16* gA = &A[(size_t)(row0 + wave * 32 + srow) * K + ((schunk ^ srow) * 8)];
  const f16* gB = &Bt[(size_t)(col0 + wave * 32 + srow) * K + ((schunk ^ srow) * 8)];
  char* asb = (char*)As;
  char* bsb = (char*)Bs;

  f32x4 acc[4][4];
  #pragma unroll
  for (int m = 0; m < 4; ++m)
    #pragma unroll
    for (int n = 0; n < 4; ++n)
      acc[m][n] = (f32x4){0.f, 0.f, 0.f, 0.f};

  const int nk = K >> 6;
  #pragma unroll
  for (int i = 0; i < 4; ++i) {
    gload16(gA + (size_t)(i * 8) * K, asb + wave * 4096 + i * 1024);
    gload16(gB + (size_t)(i * 8) * K, bsb + wave * 4096 + i * 1024);
  }
  __syncthreads();

  int cur = 0;
  for (int kt = 0; kt < nk; ++kt) {
    if (kt + 1 < nk) {
      int nb = cur ^ 1;
      #pragma unroll
      for (int i = 0; i < 4; ++i) {
        gload16(gA + (size_t)(i * 8) * K + (kt + 1) * 64, asb + nb * 16384 + wave * 4096 + i * 1024);
        gload16(gB + (size_t)(i * 8) * K + (kt + 1) * 64, bsb + nb * 16384 + wave * 4096 + i * 1024);
      }
    }
    const char* ab = asb + cur * 16384;
    const char* bb = bsb + cur * 16384;
    #pragma unroll
    for (int ks = 0; ks < 2; ++ks) {
      half8 af[4], bf[4];
      #pragma unroll
      for (int m = 0; m < 4; ++m) {
        int ar = wr * 64 + m * 16 + lr;
        af[m] = *(const half8*)(ab + ar * 128 + (((ks * 4 + hi4) ^ (ar & 7)) << 4));
      }
      #pragma unroll
      for (int n = 0; n < 4; ++n) {
        int br = wc * 64 + n * 16 + lr;
        bf[n] = *(const half8*)(bb + br * 128 + (((ks * 4 + hi4) ^ (br & 7)) << 4));
      }
      #pragma unroll
      for (int m = 0; m < 4; ++m)
        #pragma unroll
        for (int n = 0; n < 4; ++n)
          acc[m][n] = __builtin_amdgcn_mfma_f32_16x16x32_f16(af[m], bf[n], acc[m][n], 0, 0, 0);
    }
    __syncthreads();
    cur ^= 1;
  }
  #pragma unroll
  for (int m = 0; m < 4; ++m)
    #pragma unroll
    for (int n = 0; n < 4; ++n)
      #pragma unroll
      for (int j = 0; j < 4; ++j) {
        int row = row0 + wr * 64 + m * 16 + hi4 * 4 + j;
        int col = col0 + wc * 64 + n * 16 + lr;
        if (writeF32) C32[(size_t)row * N + col] = acc[m][n][j];
        else          C16[(size_t)row * N + col] = (f16)acc[m][n][j];
      }
  (void)M;
}

// ------------- RoPE, vectorized: half8 loads/stores, float4 cos/sin -------------
// thread = one (b,s,head,octet): 8 lower-half + 8 upper-half elements.
__global__ void k_rope(const f16* __restrict__ qkv, const float* __restrict__ cosb,
                       const float* __restrict__ sinb, f16* __restrict__ Qf, f16* __restrict__ Kf)
{
  const int idx = blockIdx.x * 256 + threadIdx.x;   // B*S*32*8 = 1048576 total
  const int oct = idx & 7;
  const int h = (idx >> 3) & 31;                    // 0..15 q, 16..31 k
  const int bs = idx >> 8;
  const int s = bs & (S_ - 1), b = bs >> 11;
  const f16* base = qkv + (size_t)bs * EQ_ + h * HD_;
  half8 lo = *(const half8*)(base + oct * 8);
  half8 hi = *(const half8*)(base + 64 + oct * 8);
  const float* cl = cosb + s * HD_ + oct * 8;
  const float* sl = sinb + s * HD_ + oct * 8;
  float c[8], cu[8], sn[8], su[8];
  ((float4*)c)[0]  = *(const float4*)(cl);      ((float4*)c)[1]  = *(const float4*)(cl + 4);
  ((float4*)cu)[0] = *(const float4*)(cl + 64); ((float4*)cu)[1] = *(const float4*)(cl + 68);
  ((float4*)sn)[0] = *(const float4*)(sl);      ((float4*)sn)[1] = *(const float4*)(sl + 4);
  ((float4*)su)[0] = *(const float4*)(sl + 64); ((float4*)su)[1] = *(const float4*)(sl + 68);
  const float scale = (h < H_) ? SCALE_Q : 1.0f;
  half8 olo, ohi;
  #pragma unroll
  for (int j = 0; j < 8; ++j) {
    float x = (float)lo[j], xp = (float)hi[j];
    olo[j] = (f16)((x * c[j] - xp * sn[j]) * scale);
    ohi[j] = (f16)((xp * cu[j] + x * su[j]) * scale);
  }
  f16* dst = (h < H_) ? Qf : Kf;
  const size_t off = ((size_t)(b * H_ + (h & 15)) * S_ + s) * HD_;
  *(half8*)(dst + off + oct * 8) = olo;
  *(half8*)(dst + off + 64 + oct * 8) = ohi;
}

// ---------------- V transpose: qkv v-heads -> VT[B][H][D][S] fp16 ----------------
__global__ void k_vtrans(const f16* __restrict__ qkv, f16* __restrict__ VT)
{
  __shared__ __attribute__((aligned(16))) f16 tile[128][136];
  const int bx = blockIdx.x;              // B*H*(S/128) = 512
  const int st = bx & 15, h = (bx >> 4) & 15, b = bx >> 8;
  const int t = threadIdx.x;
  const int sl = t >> 1, dc = (t & 1) * 64;
  const int bs = b * S_ + st * 128 + sl;
  #pragma unroll
  for (int i = 0; i < 8; ++i) {
    half8 v = *(const half8*)&qkv[(size_t)bs * EQ_ + (32 + h) * HD_ + dc + i * 8];
    *(half8*)&tile[sl][dc + i * 8] = v;
  }
  __syncthreads();
  const int dr = t >> 1, scc = (t & 1) * 64;
  #pragma unroll
  for (int i = 0; i < 8; ++i) {
    half8 v;
    #pragma unroll
    for (int j = 0; j < 8; ++j) v[j] = tile[scc + i * 8 + j][dr];
    *(half8*)&VT[(((size_t)(b * H_ + h)) * HD_ + dr) * S_ + st * 128 + scc + i * 8] = v;
  }
}

// ---------------- flash attention: 4 waves x 32 q-rows, KT=64 ----------------
// Head-major block remap (L2 locality), gload_lds staging w/ pre-swizzled
// source, counted vmcnt(4) K-first wait, DPP reductions, defer-max.
__global__ __launch_bounds__(256, 2) void k_attn(
    const f16* __restrict__ Qf, const f16* __restrict__ Kf, const f16* __restrict__ VT,
    f16* __restrict__ Oout)
{
  __shared__ __attribute__((aligned(16))) char lds[32768];
  char* Ks = lds;                        // [64 tok][128 d], 256B rows, chunk^(row&7)
  char* Vs = lds + 16384;                // [128 d][64 tok], 128B rows, chunk^(row&7)
  const int bx = blockIdx.x;             // B*H*(S/128) = 512
  const int hg = bx & 31, qt = bx >> 5;  // head-major: same head => same XCD residue
  const int h = hg & 15, b = hg >> 4;
  const int t = threadIdx.x, lane = t & 63, wave = t >> 6;
  const int lr = lane & 15, hi4 = lane >> 4;
  char* Ps = Ks + wave * 4096;           // after QK: per-wave [32 q][64 tok] swizzled
  const size_t bh = (size_t)(b * H_ + h);
  const int q0 = qt * 128 + wave * 32;

  half8 qf[2][4];
  #pragma unroll
  for (int m = 0; m < 2; ++m)
    #pragma unroll
    for (int ds = 0; ds < 4; ++ds)
      qf[m][ds] = *(const half8*)&Qf[(bh * S_ + q0 + m * 16 + lr) * HD_ + ds * 32 + hi4 * 8];

  f32x4 o[2][8];
  #pragma unroll
  for (int m = 0; m < 2; ++m)
    #pragma unroll
    for (int dc = 0; dc < 8; ++dc) o[m][dc] = (f32x4){0.f, 0.f, 0.f, 0.f};
  float mstate[2][4], lstate[2][4];
  #pragma unroll
  for (int m = 0; m < 2; ++m)
    #pragma unroll
    for (int j = 0; j < 4; ++j) { mstate[m][j] = -1e30f; lstate[m][j] = 0.f; }

  const f16* Kg = &Kf[bh * S_ * HD_];
  const f16* Vg = &VT[bh * HD_ * S_];

  for (int kt = 0; kt < S_ / 64; ++kt) {
    __syncthreads();   // prior PV reads done before staging overwrites K/V
    #pragma unroll
    for (int i = 0; i < 4; ++i) {
      int row = wave * 16 + i * 4 + (lane >> 4);
      int ch  = (lane & 15) ^ (row & 7);
      gload16(Kg + (size_t)(kt * 64 + row) * HD_ + ch * 8, Ks + wave * 4096 + i * 1024);
    }
    #pragma unroll
    for (int i = 0; i < 4; ++i) {
      int d  = wave * 32 + i * 8 + (lane >> 3);
      int ch = (lane & 7) ^ (d & 7);
      gload16(Vg + (size_t)d * S_ + kt * 64 + ch * 8, Vs + wave * 4096 + i * 1024);
    }
    asm volatile("s_waitcnt vmcnt(4)" ::: "memory");
    __builtin_amdgcn_s_barrier();
    __builtin_amdgcn_sched_barrier(0);   // rule #18: keep ds_reads below

    f32x4 sc[2][4];
    #pragma unroll
    for (int m = 0; m < 2; ++m)
      #pragma unroll
      for (int n = 0; n < 4; ++n) sc[m][n] = (f32x4){0.f, 0.f, 0.f, 0.f};
    #pragma unroll
    for (int ds = 0; ds < 4; ++ds) {
      half8 kf[4];
      #pragma unroll
      for (int n = 0; n < 4; ++n) {
        int ar = n * 16 + lr;
        kf[n] = *(const half8*)(Ks + ar * 256 + ((((ds * 4 + hi4) ^ (ar & 7))) << 4));
      }
      #pragma unroll
      for (int m = 0; m < 2; ++m)
        #pragma unroll
        for (int n = 0; n < 4; ++n)
          sc[m][n] = __builtin_amdgcn_mfma_f32_16x16x32_f16(qf[m][ds], kf[n], sc[m][n], 0, 0, 0);
    }
    __syncthreads();   // drains vmcnt(0): V visible; Ks reads done -> reusable as Ps

    float mx[2][4];
    #pragma unroll
    for (int m = 0; m < 2; ++m)
      #pragma unroll
      for (int j = 0; j < 4; ++j) {
        mx[m][j] = fmaxf(fmaxf(sc[m][0][j], sc[m][1][j]), fmaxf(sc[m][2][j], sc[m][3][j]));
        mx[m][j] = red16_max(mx[m][j]);
      }
    float dmax = -1e30f;
    #pragma unroll
    for (int m = 0; m < 2; ++m)
      #pragma unroll
      for (int j = 0; j < 4; ++j)
        dmax = fmaxf(dmax, mx[m][j] - mstate[m][j]);
    if (__any(dmax > DEFER_THR)) {
      #pragma unroll
      for (int m = 0; m < 2; ++m)
        #pragma unroll
        for (int j = 0; j < 4; ++j) {
          float nm = fmaxf(mstate[m][j], mx[m][j]);
          float corr = __expf(mstate[m][j] - nm);
          mstate[m][j] = nm;
          lstate[m][j] *= corr;
          #pragma unroll
          for (int dc = 0; dc < 8; ++dc) o[m][dc][j] *= corr;
        }
    }
    float rs[2][4];
    #pragma unroll
    for (int m = 0; m < 2; ++m)
      #pragma unroll
      for (int j = 0; j < 4; ++j) rs[m][j] = 0.f;
    #pragma unroll
    for (int m = 0; m < 2; ++m)
      #pragma unroll
      for (int n = 0; n < 4; ++n)
        #pragma unroll
        for (int j = 0; j < 4; ++j) {
          float p = __expf(sc[m][n][j] - mstate[m][j]);
          sc[m][n][j] = p;
          rs[m][j] += p;
        }
    #pragma unroll
    for (int m = 0; m < 2; ++m)
      #pragma unroll
      for (int j = 0; j < 4; ++j)
        lstate[m][j] += red16_sum(rs[m][j]);

    #pragma unroll
    for (int m = 0; m < 2; ++m)
      #pragma unroll
      for (int n = 0; n < 4; ++n)
        #pragma unroll
        for (int j = 0; j < 4; ++j) {
          int prow = m * 16 + hi4 * 4 + j;
          *(f16*)(Ps + prow * 128 + ((n * 32 + lr * 2) ^ ((prow & 7) << 4))) = (f16)sc[m][n][j];
        }
    asm volatile("" ::: "memory");  // per-wave LDS ordering: DS ops in-order per wave

    #pragma unroll
    for (int ks = 0; ks < 2; ++ks) {
      half8 pa[2];
      #pragma unroll
      for (int m = 0; m < 2; ++m) {
        int pr = m * 16 + lr;
        pa[m] = *(const half8*)(Ps + pr * 128 + ((((ks * 4 + hi4) ^ (pr & 7))) << 4));
      }
      #pragma unroll
      for (int dc = 0; dc < 8; ++dc) {
        int rv = dc * 16 + lr;
        half8 vb = *(const half8*)(Vs + rv * 128 + ((((ks * 4 + hi4) ^ (rv & 7))) << 4));
        #pragma unroll
        for (int m = 0; m < 2; ++m)
          o[m][dc] = __builtin_amdgcn_mfma_f32_16x16x32_f16(pa[m], vb, o[m][dc], 0, 0, 0);
      }
    }
  }

  float inv[2][4];
  #pragma unroll
  for (int m = 0; m < 2; ++m)
    #pragma unroll
    for (int j = 0; j < 4; ++j) inv[m][j] = 1.0f / lstate[m][j];
  #pragma unroll
  for (int m = 0; m < 2; ++m)
    #pragma unroll
    for (int dc = 0; dc < 8; ++dc)
      #pragma unroll
      for (int j = 0; j < 4; ++j) {
        int row = b * S_ + qt * 128 + wave * 32 + m * 16 + hi4 * 4 + j;
        int col = h * 128 + dc * 16 + lr;
        Oout[(size_t)row * DM_ + col] = (f16)(o[m][dc][j] * inv[m][j]);
      }
}

extern "C" void kernel_launch(void* const* d_in, const int* in_sizes, int n_in,
                              void* d_out, int out_size, void* d_ws, size_t ws_size,
                              hipStream_t stream) {
  (void)in_sizes; (void)n_in; (void)out_size; (void)ws_size;
  const float* hidden = (const float*)d_in[0];
  const float* cosb   = (const float*)d_in[1];
  const float* sinb   = (const float*)d_in[2];
  const float* W_qkv  = (const float*)d_in[3];
  const float* W_o    = (const float*)d_in[4];
  float* out = (float*)d_out;

  f16* Ah    = (f16*)d_ws;                 // [4096][2048]
  f16* Wqt   = Ah    + (size_t)8388608;    // [6144][2048]
  f16* Wot   = Wqt   + (size_t)12582912;   // [2048][2048]
  f16* qkv16 = Wot   + (size_t)4194304;    // [4096][6144]
  f16* Qf    = qkv16 + (size_t)25165824;   // [2][16][2048][128]
  f16* Kf    = Qf    + (size_t)8388608;
  f16* VT    = Kf    + (size_t)8388608;    // [2][16][128][2048]
  f16* AO    = VT    + (size_t)8388608;    // [4096][2048]

  k_cast<<<2048, 256, 0, stream>>>(hidden, Ah, 2097152);
  k_tcast<<<dim3(EQ_ / 64, 2048 / 64), 256, 0, stream>>>(W_qkv, Wqt, 2048, EQ_);
  k_tcast<<<dim3(2048 / 64, 2048 / 64), 256, 0, stream>>>(W_o, Wot, 2048, 2048);
  k_gemm256<<<dim3(16, 24), 512, 0, stream>>>(Ah, Wqt, qkv16, EQ_, 2048);
  k_rope<<<4096, 256, 0, stream>>>(qkv16, cosb, sinb, Qf, Kf);
  k_vtrans<<<512, 256, 0, stream>>>(qkv16, VT);
  k_attn<<<512, 256, 0, stream>>>(Qf, Kf, VT, AO);
  k_gemm<<<dim3(32, 16), 256, 0, stream>>>(AO, Wot, nullptr, out, 4096, 2048, 2048, 1);
}